// Round 8
// baseline (668.774 us; speedup 1.0000x reference)
//
#include <hip/hip_runtime.h>

#define T_LEN 2048
#define B_SZ  64
#define I_DIM 128
#define H_DIM 256

typedef _Float16 f16;
typedef _Float16 f16x8 __attribute__((ext_vector_type(8)));
typedef float    f32x4 __attribute__((ext_vector_type(4)));
typedef int      i32x4 __attribute__((ext_vector_type(4)));

__device__ __forceinline__ float fast_sigmoid(float z) {
  return __builtin_amdgcn_rcpf(1.0f + __expf(-z));
}

// ---------------------------------------------------------------------------
// Kernel 1: xproj[t][b][:] = x[b][t][:] @ Wx + bias   (written into d_out)
// grid (16, 64): blockIdx.x = 128-t chunk, blockIdx.y = b. 256 thr = 4 waves.
// Wave w owns cols [64w, 64w+64).   (f16 MFMA is right here: M=16 tile full)
// ---------------------------------------------------------------------------
__global__ __launch_bounds__(256) void xproj_kernel(
    const float* __restrict__ x, const float* __restrict__ W,
    const float* __restrict__ bias, float* __restrict__ out) {
  const int b    = blockIdx.y;
  const int tc   = blockIdx.x * 128;
  const int w    = threadIdx.x >> 6;
  const int lane = threadIdx.x & 63;
  const int cl   = lane & 15;
  const int kh   = lane >> 4;

  // Wx fragments: B[k][c], c = 64w+16g+cl, k = 32q+8kh+j (8 consecutive k/lane)
  f16x8 Bf[4][4];
#pragma unroll
  for (int g = 0; g < 4; ++g) {
    const int c = 64 * w + 16 * g + cl;
#pragma unroll
    for (int q = 0; q < 4; ++q)
#pragma unroll
      for (int j = 0; j < 8; ++j)
        Bf[g][q][j] = (f16)W[(32 * q + 8 * kh + j) * H_DIM + c];
  }
  float bv[4];
#pragma unroll
  for (int g = 0; g < 4; ++g) bv[g] = bias[64 * w + 16 * g + cl];

#pragma unroll 1
  for (int tb = 0; tb < 128; tb += 16) {
    const int t0 = tc + tb;
    // A fragments: A[r][k] = x[b][t0+r][k], r = cl, k = 8kh+j+32q
    const float* xrow = x + ((size_t)b * T_LEN + (t0 + cl)) * I_DIM + 8 * kh;
    f16x8 Af[4];
#pragma unroll
    for (int q = 0; q < 4; ++q) {
      float4 u0 = *(const float4*)(xrow + 32 * q);
      float4 u1 = *(const float4*)(xrow + 32 * q + 4);
      f16x8 a;
      a[0] = (f16)u0.x; a[1] = (f16)u0.y; a[2] = (f16)u0.z; a[3] = (f16)u0.w;
      a[4] = (f16)u1.x; a[5] = (f16)u1.y; a[6] = (f16)u1.z; a[7] = (f16)u1.w;
      Af[q] = a;
    }
#pragma unroll
    for (int g = 0; g < 4; ++g) {
      f32x4 acc = {0.f, 0.f, 0.f, 0.f};
#pragma unroll
      for (int q = 0; q < 4; ++q)
        acc = __builtin_amdgcn_mfma_f32_16x16x32_f16(Af[q], Bf[g][q], acc, 0, 0, 0);
      // D: row = 4kh+j, col = cl (+16g+64w)
#pragma unroll
      for (int j = 0; j < 4; ++j) {
        const int t = t0 + 4 * kh + j;
        out[((size_t)t * B_SZ + b) * H_DIM + 64 * w + 16 * g + cl] = acc[j] + bv[g];
      }
    }
  }
}

// ---------------------------------------------------------------------------
// Kernel 2: sequential scan — i8 MFMA with own-chunk latency overlap.
//
// r7 structure (i8 16x16x64 fixed-point, 4 waves, 4 tiles/wave, multi-row
// shared-A) + the overlap trick: wave w itself produces h for columns
// 64w..64w+63 = K-chunk w of the NEXT step's reduction. So after writing
// h_t to LDS, wave w immediately re-reads its OWN A-fragment (same-wave DS
// ops complete in order -> no barrier needed), and the pre-barrier waitcnt
// is lgkmcnt(1): drain the write, leave the own-read in flight ACROSS the
// barrier (counted-lgkm, T4-style). Post-barrier: issue the 3 other-chunk
// reads first, then run the 4 own-chunk MFMAs (compiler waits lgkmcnt(3))
// so their ~80 cyc of issue covers the other chunks' ~120-cyc read latency.
// Bq is stored per-wave in ROTATED chunk order (BqR[g][r] <-> chunk (w+r)&3)
// so every register index is compile-time static (no scratch).
//
// Fixed-point encoding (absmax floor-equal to f16, verified r7):
//   hq = round(h*254) - 127 ; wq = round(Wh*2490)
//   z  = idot/(254*2490) + zoff + xp,  zoff = 127*colsum/(254*2490)
// ---------------------------------------------------------------------------
#define MFMAI8(A, B, C) __builtin_amdgcn_mfma_i32_16x16x64_i8((A), (B), (C), 0, 0, 0)

#define SW_SCALE 2490.0f
#define INVS (1.0f / (254.0f * SW_SCALE))
#define RS (B_SZ * H_DIM)

// Barrier that drains the h-write but leaves the own-chunk ds_read in
// flight (1 outstanding DS op; DS completes in-order within a wave).
#define WG_BARRIER_K1() do {                               \
  asm volatile("s_waitcnt lgkmcnt(1)" ::: "memory");       \
  __builtin_amdgcn_s_barrier();                            \
  asm volatile("" ::: "memory");                           \
  __builtin_amdgcn_sched_barrier(0);                       \
} while (0)

#define RNN_STEP(pp, RB) do {                                                \
  if (rdlane) {                                                              \
    Aq1 = *(const i32x4*)&hbuf8[RB][rd1];                                    \
    Aq2 = *(const i32x4*)&hbuf8[RB][rd2];                                    \
    Aq3 = *(const i32x4*)&hbuf8[RB][rd3];                                    \
  }                                                                          \
  i32x4 a0 = MFMAI8(AqOwn, BqR[0][0], Zacc);                                 \
  i32x4 a1 = MFMAI8(AqOwn, BqR[1][0], Zacc);                                 \
  i32x4 a2 = MFMAI8(AqOwn, BqR[2][0], Zacc);                                 \
  i32x4 a3 = MFMAI8(AqOwn, BqR[3][0], Zacc);                                 \
  a0 = MFMAI8(Aq1, BqR[0][1], a0);                                           \
  a1 = MFMAI8(Aq1, BqR[1][1], a1);                                           \
  a2 = MFMAI8(Aq1, BqR[2][1], a2);                                           \
  a3 = MFMAI8(Aq1, BqR[3][1], a3);                                           \
  a0 = MFMAI8(Aq2, BqR[0][2], a0);                                           \
  a1 = MFMAI8(Aq2, BqR[1][2], a1);                                           \
  a2 = MFMAI8(Aq2, BqR[2][2], a2);                                           \
  a3 = MFMAI8(Aq2, BqR[3][2], a3);                                           \
  a0 = MFMAI8(Aq3, BqR[0][3], a0);                                           \
  a1 = MFMAI8(Aq3, BqR[1][3], a1);                                           \
  a2 = MFMAI8(Aq3, BqR[2][3], a2);                                           \
  a3 = MFMAI8(Aq3, BqR[3][3], a3);                                           \
  int idot = g1 ? a1[0] : a0[0];                                             \
  idot = g2 ? a2[0] : idot;                                                  \
  idot = g3 ? a3[0] : idot;                                                  \
  float hh = fast_sigmoid(__builtin_fmaf((float)idot, INVS, zoff + (pp)));   \
  int hq = (int)__builtin_rintf(__builtin_fmaf(hh, 254.0f, -127.0f));        \
  hbuf8[(RB) ^ 1][tid] = (signed char)hq;                                    \
  if (rdlane) AqOwn = *(const i32x4*)&hbuf8[(RB) ^ 1][rdOwn];                \
  WG_BARRIER_K1();                                                           \
  *opSt = hh; opSt += RS;                                                    \
} while (0)

__global__ __launch_bounds__(256, 1) void rnn_kernel(
    const float* __restrict__ W, float* out) {
  const int b    = blockIdx.x;
  const int tid  = threadIdx.x;
  const int w    = tid >> 6;
  const int lane = tid & 63;
  const int cl   = lane & 15;
  const int kh   = lane >> 4;

  __shared__ __align__(16) signed char hbuf8[2][H_DIM];
  // h0 = 0  ->  hq = round(0*254) - 127 = -127
  hbuf8[0][tid] = (signed char)-127;
  hbuf8[1][tid] = (signed char)-127;

  // Quantized Wh fragments in ROTATED chunk order: BqR[g][r] holds K-chunk
  // (w+r)&3 for tile g (c = 64w+16g+cl, k = 64*chunk + 16kh + 4d + j).
  // 4 tiles x 4 r x 4 VGPR = 64 VGPRs, all statically indexed.
  i32x4 BqR[4][4];
#pragma unroll
  for (int g = 0; g < 4; ++g) {
    const int c = 64 * w + 16 * g + cl;
#pragma unroll
    for (int r = 0; r < 4; ++r) {
      const int chunk = (w + r) & 3;
#pragma unroll
      for (int d = 0; d < 4; ++d) {
        int dw = 0;
#pragma unroll
        for (int j = 0; j < 4; ++j) {
          const int k = 64 * chunk + 16 * kh + 4 * d + j;
          const int qv = (int)__builtin_rintf(W[(I_DIM + k) * H_DIM + c] * SW_SCALE);
          dw |= (qv & 0xff) << (8 * j);
        }
        BqR[g][r][d] = dw;
      }
    }
  }

  // Per-thread column constant: zoff = 127 * colsum(c=tid) * INVS.
  int cs = 0;
#pragma unroll 4
  for (int k = 0; k < H_DIM; ++k)
    cs += (int)__builtin_rintf(W[(I_DIM + k) * H_DIM + tid] * SW_SCALE);
  const float zoff = 127.0f * (float)cs * INVS;

  // A fragments (named, static): own chunk + 3 others. Non-reader lanes keep
  // zeros; garbage in unused A-rows would be harmless (their D-rows are never
  // consumed) but zero-init keeps things deterministic.
  i32x4 AqOwn = {0, 0, 0, 0};
  i32x4 Aq1 = {0, 0, 0, 0}, Aq2 = {0, 0, 0, 0}, Aq3 = {0, 0, 0, 0};
  const i32x4 Zacc = {0, 0, 0, 0};

  const bool rdlane = ((cl & 3) == 0);
  const int  rdOwn = 64 * w + 16 * kh;
  const int  rd1   = 64 * ((w + 1) & 3) + 16 * kh;
  const int  rd2   = 64 * ((w + 2) & 3) + 16 * kh;
  const int  rd3   = 64 * ((w + 3) & 3) + 16 * kh;

  // z-selection masks: lane group picks its tile's accumulator.
  const bool g1 = (lane >> 4) == 1;
  const bool g2 = (lane >> 4) == 2;
  const bool g3 = (lane >> 4) == 3;

  float* op    = out + (size_t)b * H_DIM + tid;  // &out[(t*B+b)*H + tid], t=0
  float* opSt  = op;
  const float* opPre = op + 4 * (size_t)RS;

  __syncthreads();

  // xp prefetch pipeline, depth 4 (fully coalesced 1KB per WG)
  float p0 = op[0 * (size_t)RS];
  float p1 = op[1 * (size_t)RS];
  float p2 = op[2 * (size_t)RS];
  float p3 = op[3 * (size_t)RS];

  // initial own-chunk read of h_0 (same-wave ordering after __syncthreads)
  if (rdlane) AqOwn = *(const i32x4*)&hbuf8[0][rdOwn];

  // main loop: t = 0..2043 (511 x 4 steps), prefetch rows t+4..t+7
#pragma unroll 1
  for (int it = 0; it < (T_LEN - 4) / 4; ++it) {
    float n0 = opPre[0 * (size_t)RS];
    RNN_STEP(p0, 0); p0 = n0;
    float n1 = opPre[1 * (size_t)RS];
    RNN_STEP(p1, 1); p1 = n1;
    float n2 = opPre[2 * (size_t)RS];
    RNN_STEP(p2, 0); p2 = n2;
    float n3 = opPre[3 * (size_t)RS];
    RNN_STEP(p3, 1); p3 = n3;
    opPre += 4 * (size_t)RS;
  }
  // epilogue: t = 2044..2047, no prefetch
  RNN_STEP(p0, 0);
  RNN_STEP(p1, 1);
  RNN_STEP(p2, 0);
  RNN_STEP(p3, 1);
}

extern "C" void kernel_launch(void* const* d_in, const int* in_sizes, int n_in,
                              void* d_out, int out_size, void* d_ws, size_t ws_size,
                              hipStream_t stream) {
  (void)in_sizes; (void)n_in; (void)d_ws; (void)ws_size; (void)out_size;
  const float* x    = (const float*)d_in[0];
  const float* W    = (const float*)d_in[1];
  const float* bias = (const float*)d_in[2];
  float* out = (float*)d_out;

  xproj_kernel<<<dim3(16, 64), 256, 0, stream>>>(x, W, bias, out);
  rnn_kernel<<<64, 256, 0, stream>>>(W, out);
}